// Round 2
// baseline (236.821 us; speedup 1.0000x reference)
//
#include <hip/hip_runtime.h>

#define NB 4
#define NL 1024
#define NH 8
#define ND 64
#define NBH 32   // NB*NH

typedef __attribute__((ext_vector_type(8))) short bhalf8;
typedef __attribute__((ext_vector_type(4))) float f32x4;

static __device__ inline unsigned short f2bf(float f) {
    union { float f; unsigned u; } x; x.f = f;
    unsigned r = x.u + 0x7FFFu + ((x.u >> 16) & 1u);   // round-nearest-even
    return (unsigned short)(r >> 16);
}

// ---------------------------------------------------------------------------
// Kernel 1: L2-normalize q (with 1/(T*ln2) folded in, so attn uses exp2) and
// k; transpose [B,L,H,D] -> head-major [B,H,L,D] bf16. One wave per row.
// ---------------------------------------------------------------------------
__global__ __launch_bounds__(256) void norm_qk_kernel(const float* __restrict__ q,
                                                      const float* __restrict__ k,
                                                      unsigned short* __restrict__ qn,
                                                      unsigned short* __restrict__ kn) {
    int wid  = threadIdx.x >> 6;
    int lane = threadIdx.x & 63;
    int r = blockIdx.x * 4 + wid;            // row over (b,l,h), 0..32767
    int b = r >> 13;                         // / (L*H)
    int l = (r >> 3) & (NL - 1);
    int h = r & (NH - 1);

    float qv = q[(size_t)r * ND + lane];
    float kv = k[(size_t)r * ND + lane];
    float qs = qv * qv, ks = kv * kv;
    #pragma unroll
    for (int m = 1; m < 64; m <<= 1) {
        qs += __shfl_xor(qs, m);
        ks += __shfl_xor(ks, m);
    }
    // fold 1/TEMPERATURE and 1/ln(2): softmax(x/8) == softmax2(x/(8 ln2))
    float qd = 1.0f / (fmaxf(sqrtf(qs), 1e-8f) * 5.545177444479562f);
    float kd = 1.0f / fmaxf(sqrtf(ks), 1e-8f);

    size_t o = ((size_t)(b * NH + h) * NL + l) * ND + lane;
    qn[o] = f2bf(qv * qd);
    kn[o] = f2bf(kv * kd);
}

// ---------------------------------------------------------------------------
// Kernel 2: v [B,L,H,D] fp32 -> vt [B,H,D,L] bf16 via LDS tile transpose.
// Grid (NBH, NL/64), block 1024 (16 waves -> 32 waves/CU at 2 blocks/CU).
// ---------------------------------------------------------------------------
__global__ __launch_bounds__(1024) void vtrans_kernel(const float* __restrict__ v,
                                                      unsigned short* __restrict__ vt) {
    __shared__ float tile[64 * 65];
    int bh = blockIdx.x;
    int b = bh >> 3, h = bh & 7;
    int l0 = blockIdx.y * 64;
    int wid = threadIdx.x >> 6, lane = threadIdx.x & 63;

    #pragma unroll
    for (int rr = 0; rr < 4; ++rr) {
        int row = wid * 4 + rr;
        float val = v[(((size_t)b * NL + l0 + row) * NH + h) * ND + lane];
        tile[lane * 65 + row] = val;
    }
    __syncthreads();
    #pragma unroll
    for (int dd = 0; dd < 4; ++dd) {
        int d = wid * 4 + dd;
        vt[((size_t)(bh * ND + d)) * NL + l0 + lane] = f2bf(tile[d * 65 + lane]);
    }
}

// ---------------------------------------------------------------------------
// Kernel 3: fused cosine attention. Grid (NBH, NL/16) = (32,64), block 256.
// One block per 16 query rows; the 4 waves split the KEY dimension (256 keys
// each) -> 8192 waves = 32 waves/CU (was 8/CU in R0 -> 21% occupancy).
// Pass 1: partial softmax denominators per wave, block-reduced in LDS.
// Pass 2: recompute scores (K is L2-resident), write attn, P through LDS
// (C-layout -> A-layout), accumulate partial PV; block-reduce O in LDS.
// LDS: o-accumulator (4 waves x 16 x 66 fp32 = 16.9 KB) aliases the P-tiles
// (5.1 KB) -> ~17.2 KB/block, 9 blocks/CU by LDS (not the occupancy limit).
// ---------------------------------------------------------------------------
__global__ __launch_bounds__(256) void attn_kernel(const unsigned short* __restrict__ qn,
                                                   const unsigned short* __restrict__ kn,
                                                   const unsigned short* __restrict__ vt,
                                                   float* __restrict__ outp,
                                                   float* __restrict__ attnp) {
    __shared__ __align__(16) unsigned char smem_raw[4 * 16 * 66 * 4];  // 16896 B
    __shared__ float dred[4][16];
    __shared__ float invd[16];

    unsigned short* ptile = (unsigned short*)smem_raw;  // [4][16*40] while in pass 2
    float*          oaccf = (float*)smem_raw;           // [4][16*66] after pass 2

    int bh   = blockIdx.x;                   // 0..31
    int wid  = threadIdx.x >> 6;             // wave -> key-range owner
    int lane = threadIdx.x & 63;
    int c    = lane & 15;
    int quad = lane >> 4;
    int m0   = blockIdx.y * 16;              // q-tile base row

    unsigned short* myp = ptile + wid * (16 * 40);

    // A-frag of Q: lane holds A[m=c][k=quad*8+j]
    const unsigned short* qbase = qn + ((size_t)(bh * NL + m0 + c)) * ND + quad * 8;
    bhalf8 qa0 = *(const bhalf8*)(qbase);
    bhalf8 qa1 = *(const bhalf8*)(qbase + 32);

    const unsigned short* kbh = kn + (size_t)bh * NL * ND;

    // ---- pass 1: partial denominators over this wave's 256 keys ----
    float denom[4] = {0.f, 0.f, 0.f, 0.f};
    for (int jt = 0; jt < 16; ++jt) {
        int j0 = wid * 256 + jt * 16;
        const unsigned short* kb = kbh + ((size_t)(j0 + c)) * ND + quad * 8;
        bhalf8 kf0 = *(const bhalf8*)(kb);
        bhalf8 kf1 = *(const bhalf8*)(kb + 32);
        f32x4 s = {0.f, 0.f, 0.f, 0.f};
        s = __builtin_amdgcn_mfma_f32_16x16x32_bf16(qa0, kf0, s, 0, 0, 0);
        s = __builtin_amdgcn_mfma_f32_16x16x32_bf16(qa1, kf1, s, 0, 0, 0);
        #pragma unroll
        for (int r = 0; r < 4; ++r) denom[r] += __builtin_amdgcn_exp2f(s[r]);
    }
    #pragma unroll
    for (int r = 0; r < 4; ++r) {
        float d = denom[r];
        d += __shfl_xor(d, 1);
        d += __shfl_xor(d, 2);
        d += __shfl_xor(d, 4);
        d += __shfl_xor(d, 8);               // sum over the 16 col-lanes of this quad
        denom[r] = d;
    }
    if (c == 0) {
        #pragma unroll
        for (int r = 0; r < 4; ++r) dred[wid][quad * 4 + r] = denom[r];
    }
    __syncthreads();
    if (threadIdx.x < 16) {
        invd[threadIdx.x] = 1.0f / (dred[0][threadIdx.x] + dred[1][threadIdx.x] +
                                    dred[2][threadIdx.x] + dred[3][threadIdx.x]);
    }
    __syncthreads();
    float inv[4];
    #pragma unroll
    for (int r = 0; r < 4; ++r) inv[r] = invd[quad * 4 + r];

    // ---- pass 2: attn write + partial PV over this wave's 256 keys ----
    float* attnrow = attnp + ((size_t)(bh * NL + m0)) * NL;
    const unsigned short* vbh = vt + (size_t)bh * ND * NL;

    f32x4 o[4] = {{0.f,0.f,0.f,0.f},{0.f,0.f,0.f,0.f},{0.f,0.f,0.f,0.f},{0.f,0.f,0.f,0.f}};
    for (int j2 = 0; j2 < 8; ++j2) {
        int jb = wid * 256 + j2 * 32;
        #pragma unroll
        for (int sub = 0; sub < 2; ++sub) {
            int j0 = jb + sub * 16;
            const unsigned short* kb = kbh + ((size_t)(j0 + c)) * ND + quad * 8;
            bhalf8 kf0 = *(const bhalf8*)(kb);
            bhalf8 kf1 = *(const bhalf8*)(kb + 32);
            f32x4 s = {0.f, 0.f, 0.f, 0.f};
            s = __builtin_amdgcn_mfma_f32_16x16x32_bf16(qa0, kf0, s, 0, 0, 0);
            s = __builtin_amdgcn_mfma_f32_16x16x32_bf16(qa1, kf1, s, 0, 0, 0);
            #pragma unroll
            for (int r = 0; r < 4; ++r) {
                float a = __builtin_amdgcn_exp2f(s[r]) * inv[r];
                attnrow[(size_t)(quad * 4 + r) * NL + j0 + c] = a;
                myp[(quad * 4 + r) * 40 + sub * 16 + c] = f2bf(a);
            }
        }
        // C-layout -> A-layout round trip (same-wave LDS r/w)
        bhalf8 pa = *(const bhalf8*)(myp + c * 40 + quad * 8);
        #pragma unroll
        for (int nt = 0; nt < 4; ++nt) {
            const unsigned short* vb = vbh + (size_t)(nt * 16 + c) * NL + jb + quad * 8;
            bhalf8 vf = *(const bhalf8*)(vb);
            o[nt] = __builtin_amdgcn_mfma_f32_16x16x32_bf16(pa, vf, o[nt], 0, 0, 0);
        }
    }

    // ---- block-reduce O across the 4 waves (LDS aliases the P-tiles) ----
    __syncthreads();                         // all waves done reading their P-tile
    #pragma unroll
    for (int nt = 0; nt < 4; ++nt) {
        #pragma unroll
        for (int r = 0; r < 4; ++r) {
            oaccf[wid * 1056 + (quad * 4 + r) * 66 + nt * 16 + c] = o[nt][r];
        }
    }
    __syncthreads();
    float* obase = outp + ((size_t)(bh * NL + m0)) * ND;
    #pragma unroll
    for (int i = 0; i < 4; ++i) {
        int e = i * 256 + threadIdx.x;
        int row = e >> 6, col = e & 63;
        float s = oaccf[row * 66 + col] + oaccf[1056 + row * 66 + col] +
                  oaccf[2112 + row * 66 + col] + oaccf[3168 + row * 66 + col];
        obase[e] = s;
    }
}

// ---------------------------------------------------------------------------
extern "C" void kernel_launch(void* const* d_in, const int* in_sizes, int n_in,
                              void* d_out, int out_size, void* d_ws, size_t ws_size,
                              hipStream_t stream) {
    const float* q = (const float*)d_in[0];
    const float* k = (const float*)d_in[1];
    const float* v = (const float*)d_in[2];

    float* outp  = (float*)d_out;                              // [B,H,L,D] = 2M fp32
    float* attnp = outp + (size_t)NB * NH * NL * ND;           // [B,H,L,L] = 33.5M fp32

    unsigned short* qn = (unsigned short*)d_ws;                // 2M bf16
    unsigned short* kn = qn + (size_t)NB * NH * NL * ND;       // 2M bf16
    unsigned short* vt = kn + (size_t)NB * NH * NL * ND;       // 2M bf16

    norm_qk_kernel<<<(NB * NL * NH) / 4, 256, 0, stream>>>(q, k, qn, kn);
    vtrans_kernel<<<dim3(NBH, NL / 64), 1024, 0, stream>>>(v, vt);
    attn_kernel<<<dim3(NBH, NL / 16), 256, 0, stream>>>(qn, kn, vt, outp, attnp);
}

// Round 3
// 207.610 us; speedup vs baseline: 1.1407x; 1.1407x over previous
//
#include <hip/hip_runtime.h>

#define NB 4
#define NL 1024
#define NH 8
#define ND 64
#define NBH 32   // NB*NH

typedef __attribute__((ext_vector_type(8))) short bhalf8;
typedef __attribute__((ext_vector_type(4))) float f32x4;

static __device__ inline unsigned short f2bf(float f) {
    union { float f; unsigned u; } x; x.f = f;
    unsigned r = x.u + 0x7FFFu + ((x.u >> 16) & 1u);   // round-nearest-even
    return (unsigned short)(r >> 16);
}

// ---------------------------------------------------------------------------
// Prep kernel (merged): blocks [0,2048) = L2-normalize q,k -> bf16 head-major;
// blocks [2048,2560) = v transpose [B,L,H,D] fp32 -> [B,H,D,L] bf16.
// 256 threads everywhere; branch is block-uniform.
// ---------------------------------------------------------------------------
__global__ __launch_bounds__(256) void prep_kernel(const float* __restrict__ q,
                                                   const float* __restrict__ k,
                                                   const float* __restrict__ v,
                                                   unsigned short* __restrict__ qn,
                                                   unsigned short* __restrict__ kn,
                                                   unsigned short* __restrict__ vt) {
    int tid = threadIdx.x;
    if (blockIdx.x < 2048) {
        // ---- norm: 16 rows per block, 4 per wave, float4 I/O ----
        int w = tid >> 6, lane = tid & 63;
        int rowg = blockIdx.x * 16 + w * 4 + (lane >> 4);  // (b,l,h) row, 0..32767
        int c = lane & 15;
        float4 q4 = ((const float4*)q)[(size_t)rowg * 16 + c];
        float4 k4 = ((const float4*)k)[(size_t)rowg * 16 + c];
        float qs = q4.x*q4.x + q4.y*q4.y + q4.z*q4.z + q4.w*q4.w;
        float ks = k4.x*k4.x + k4.y*k4.y + k4.z*k4.z + k4.w*k4.w;
        #pragma unroll
        for (int m = 1; m < 16; m <<= 1) {
            qs += __shfl_xor(qs, m);
            ks += __shfl_xor(ks, m);
        }
        // fold 1/TEMPERATURE and 1/ln(2) into q: softmax(x/8) == softmax2(x/(8 ln2))
        float qd = 1.0f / (fmaxf(sqrtf(qs), 1e-8f) * 5.545177444479562f);
        float kd = 1.0f / fmaxf(sqrtf(ks), 1e-8f);
        int b = rowg >> 13, l = (rowg >> 3) & (NL - 1), h = rowg & (NH - 1);
        size_t o = ((size_t)(b * NH + h) * NL + l) * 16 + c;   // ushort4 units
        ushort4 qo, ko;
        qo.x = f2bf(q4.x * qd); qo.y = f2bf(q4.y * qd);
        qo.z = f2bf(q4.z * qd); qo.w = f2bf(q4.w * qd);
        ko.x = f2bf(k4.x * kd); ko.y = f2bf(k4.y * kd);
        ko.z = f2bf(k4.z * kd); ko.w = f2bf(k4.w * kd);
        ((ushort4*)qn)[o] = qo;
        ((ushort4*)kn)[o] = ko;
    } else {
        // ---- v transpose: 64l x 64d tile via bf16 LDS, vectorized both sides ----
        __shared__ unsigned short tile_t[64 * 68];   // [d][l], pad 4
        int bid = blockIdx.x - 2048;
        int bh = bid >> 4;
        int b = bh >> 3, h = bh & 7;
        int l0 = (bid & 15) * 64;
        #pragma unroll
        for (int i = 0; i < 4; ++i) {
            int l = (tid >> 4) + i * 16;
            int c4 = tid & 15;
            float4 vv = ((const float4*)v)[(((size_t)b * NL + l0 + l) * NH + h) * 16 + c4];
            tile_t[(c4 * 4 + 0) * 68 + l] = f2bf(vv.x);
            tile_t[(c4 * 4 + 1) * 68 + l] = f2bf(vv.y);
            tile_t[(c4 * 4 + 2) * 68 + l] = f2bf(vv.z);
            tile_t[(c4 * 4 + 3) * 68 + l] = f2bf(vv.w);
        }
        __syncthreads();
        int d = tid >> 2, lg = tid & 3;
        #pragma unroll
        for (int i = 0; i < 4; ++i) {
            ushort4 u4 = *(const ushort4*)&tile_t[d * 68 + i * 16 + lg * 4];
            ((ushort4*)vt)[((size_t)(bh * ND + d)) * (NL / 4) + l0 / 4 + i * 4 + lg] = u4;
        }
    }
}

// ---------------------------------------------------------------------------
// Attention kernel: grid (NBH, NL/16) = (32,64), block 256 (4 waves).
// Block owns 16 query rows; waves split keys (256 each). SINGLE PASS over K:
// the wave's 16x256 exp-score tile lives in VGPRs (s[16] f32x4 = 64 regs), so
// the 32 K-frag loads are independent chains the compiler can pipeline, and
// normalization + attn-store + PV need no K reload / exp recompute.
// ---------------------------------------------------------------------------
__global__ __launch_bounds__(256) void attn_kernel(const unsigned short* __restrict__ qn,
                                                   const unsigned short* __restrict__ kn,
                                                   const unsigned short* __restrict__ vt,
                                                   float* __restrict__ outp,
                                                   float* __restrict__ attnp) {
    __shared__ __align__(16) unsigned char smem_raw[4 * 16 * 66 * 4];  // 16896 B
    __shared__ float dred[4][16];
    __shared__ float invd[16];

    unsigned short* ptile = (unsigned short*)smem_raw;  // [4][16*40] during PV
    float*          oaccf = (float*)smem_raw;           // [4][16*66] in epilogue

    int bh   = blockIdx.x;
    int wid  = threadIdx.x >> 6;             // wave -> key-range owner
    int lane = threadIdx.x & 63;
    int c    = lane & 15;
    int quad = lane >> 4;
    int m0   = blockIdx.y * 16;

    unsigned short* myp = ptile + wid * (16 * 40);

    // A-frag of Q: lane holds A[m=c][k=quad*8+j]
    const unsigned short* qbase = qn + ((size_t)(bh * NL + m0 + c)) * ND + quad * 8;
    bhalf8 qa0 = *(const bhalf8*)(qbase);
    bhalf8 qa1 = *(const bhalf8*)(qbase + 32);

    const unsigned short* kbh = kn + (size_t)bh * NL * ND;

    // ---- pass 1: scores -> exp2, kept in registers; accumulate denominator ----
    f32x4 s[16];
    float denom[4] = {0.f, 0.f, 0.f, 0.f};
    #pragma unroll
    for (int jt = 0; jt < 16; ++jt) {
        int j0 = wid * 256 + jt * 16;
        const unsigned short* kb = kbh + ((size_t)(j0 + c)) * ND + quad * 8;
        bhalf8 kf0 = *(const bhalf8*)(kb);
        bhalf8 kf1 = *(const bhalf8*)(kb + 32);
        f32x4 acc = {0.f, 0.f, 0.f, 0.f};
        acc = __builtin_amdgcn_mfma_f32_16x16x32_bf16(qa0, kf0, acc, 0, 0, 0);
        acc = __builtin_amdgcn_mfma_f32_16x16x32_bf16(qa1, kf1, acc, 0, 0, 0);
        #pragma unroll
        for (int r = 0; r < 4; ++r) {
            float e = __builtin_amdgcn_exp2f(acc[r]);
            s[jt][r] = e;
            denom[r] += e;
        }
    }
    #pragma unroll
    for (int r = 0; r < 4; ++r) {
        float d = denom[r];
        d += __shfl_xor(d, 1);
        d += __shfl_xor(d, 2);
        d += __shfl_xor(d, 4);
        d += __shfl_xor(d, 8);               // sum over the 16 col-lanes of this quad
        denom[r] = d;
    }
    if (c == 0) {
        #pragma unroll
        for (int r = 0; r < 4; ++r) dred[wid][quad * 4 + r] = denom[r];
    }
    __syncthreads();
    if (threadIdx.x < 16) {
        invd[threadIdx.x] = 1.0f / (dred[0][threadIdx.x] + dred[1][threadIdx.x] +
                                    dred[2][threadIdx.x] + dred[3][threadIdx.x]);
    }
    __syncthreads();
    float inv[4];
    #pragma unroll
    for (int r = 0; r < 4; ++r) inv[r] = invd[quad * 4 + r];

    // ---- pass 2: normalize from registers, write attn, PV ----
    float* attnrow = attnp + ((size_t)(bh * NL + m0)) * NL;
    const unsigned short* vbh = vt + (size_t)bh * ND * NL;

    f32x4 o[4] = {{0.f,0.f,0.f,0.f},{0.f,0.f,0.f,0.f},{0.f,0.f,0.f,0.f},{0.f,0.f,0.f,0.f}};
    #pragma unroll
    for (int j2 = 0; j2 < 8; ++j2) {
        int jb = wid * 256 + j2 * 32;
        #pragma unroll
        for (int sub = 0; sub < 2; ++sub) {
            int j0 = jb + sub * 16;
            #pragma unroll
            for (int r = 0; r < 4; ++r) {
                float a = s[j2 * 2 + sub][r] * inv[r];
                attnrow[(size_t)(quad * 4 + r) * NL + j0 + c] = a;
                myp[(quad * 4 + r) * 40 + sub * 16 + c] = f2bf(a);
            }
        }
        // C-layout -> A-layout round trip (same-wave LDS r/w)
        bhalf8 pa = *(const bhalf8*)(myp + c * 40 + quad * 8);
        #pragma unroll
        for (int nt = 0; nt < 4; ++nt) {
            const unsigned short* vb = vbh + (size_t)(nt * 16 + c) * NL + jb + quad * 8;
            bhalf8 vf = *(const bhalf8*)(vb);
            o[nt] = __builtin_amdgcn_mfma_f32_16x16x32_bf16(pa, vf, o[nt], 0, 0, 0);
        }
    }

    // ---- block-reduce O across the 4 waves (LDS aliases the P-tiles) ----
    __syncthreads();                         // all waves done reading their P-tile
    #pragma unroll
    for (int nt = 0; nt < 4; ++nt) {
        #pragma unroll
        for (int r = 0; r < 4; ++r) {
            oaccf[wid * 1056 + (quad * 4 + r) * 66 + nt * 16 + c] = o[nt][r];
        }
    }
    __syncthreads();
    float* obase = outp + ((size_t)(bh * NL + m0)) * ND;
    #pragma unroll
    for (int i = 0; i < 4; ++i) {
        int e = i * 256 + threadIdx.x;
        int row = e >> 6, col = e & 63;
        float sum = oaccf[row * 66 + col] + oaccf[1056 + row * 66 + col] +
                    oaccf[2112 + row * 66 + col] + oaccf[3168 + row * 66 + col];
        obase[e] = sum;
    }
}

// ---------------------------------------------------------------------------
extern "C" void kernel_launch(void* const* d_in, const int* in_sizes, int n_in,
                              void* d_out, int out_size, void* d_ws, size_t ws_size,
                              hipStream_t stream) {
    const float* q = (const float*)d_in[0];
    const float* k = (const float*)d_in[1];
    const float* v = (const float*)d_in[2];

    float* outp  = (float*)d_out;                              // [B,H,L,D] = 2M fp32
    float* attnp = outp + (size_t)NB * NH * NL * ND;           // [B,H,L,L] = 33.5M fp32

    unsigned short* qn = (unsigned short*)d_ws;                // 2M bf16
    unsigned short* kn = qn + (size_t)NB * NH * NL * ND;       // 2M bf16
    unsigned short* vt = kn + (size_t)NB * NH * NL * ND;       // 2M bf16

    prep_kernel<<<2048 + 512, 256, 0, stream>>>(q, k, v, qn, kn, vt);
    attn_kernel<<<dim3(NBH, NL / 16), 256, 0, stream>>>(qn, kn, vt, outp, attnp);
}